// Round 1
// baseline (900.484 us; speedup 1.0000x reference)
//
#include <hip/hip_runtime.h>

#define B_TOTAL 4096
#define NVARS   128
#define NMOD    128
#define HID     256

typedef __attribute__((ext_vector_type(8))) __bf16 bf16x8;
typedef __attribute__((ext_vector_type(4))) float  f32x4;

// packed f32->bf16 (RNE), 2 values / instruction
__device__ __forceinline__ unsigned pk_bf16(float lo, float hi) {
    unsigned r;
    asm("v_cvt_pk_bf16_f32 %0, %1, %2" : "=v"(r) : "v"(lo), "v"(hi));
    return r;
}

__device__ __forceinline__ float lrelu(float v) { return v > 0.f ? v : 0.01f * v; }

// ---------------------------------------------------------------------------
// fp32 -> bf16 weight conversion (once per launch; weights then L2/L3-hot)
// ---------------------------------------------------------------------------
__global__ __launch_bounds__(256) void k_cvt(const float* __restrict__ in,
                                             uint2* __restrict__ out, int n4) {
    int i = blockIdx.x * 256 + threadIdx.x;
    if (i < n4) {
        float4 v = ((const float4*)in)[i];
        uint2 o;
        o.x = pk_bf16(v.x, v.y);
        o.y = pk_bf16(v.z, v.w);
        out[i] = o;
    }
}

// ---------------------------------------------------------------------------
// Xm[t][b][j] = bf16( mask_n2m[b][j][t] * x[b][j] )
// grid (b, half): each block transposes a 128j x 64t half-tile via an f32 LDS
// tile [j][t] with 16B-chunk XOR swizzle (conflict-minimal both phases).
//   phase A: coalesced float4 reads along t, float4 LDS writes (swizzled)
//   phase B: scalar f32 column reads (2-way, free), *x, cvt_pk, uint4 store
// ---------------------------------------------------------------------------
__global__ __launch_bounds__(256) void k_maskx(const float* __restrict__ mask,
                                               const float* __restrict__ x,
                                               unsigned short* __restrict__ Xm) {
    const int b    = blockIdx.x;
    const int half = blockIdx.y;          // t in [half*64, half*64+64)
    const int tid  = threadIdx.x;

    __shared__ __align__(16) float xs[NVARS];
    __shared__ __align__(16) float tile[NVARS * 64];   // [j][t_local], swizzled

    if (tid < NVARS) xs[tid] = x[(size_t)b * NVARS + tid];

    // ---- phase A: mask[b][j][half*64 + ...] -> tile ----
    const float* mrow = mask + (size_t)b * (NVARS * NMOD) + half * 64;
    #pragma unroll
    for (int it = 0; it < 8; ++it) {
        int idx4 = it * 256 + tid;        // 0..2047
        int j    = idx4 >> 4;             // 0..127
        int th4  = idx4 & 15;             // 16B chunk within the 64-float row
        float4 v = *(const float4*)(mrow + (size_t)j * NMOD + th4 * 4);
        int sw = (j ^ (j >> 3)) & 15;     // mixes j low bits AND j>>3 (needed in B)
        *(float4*)(tile + j * 64 + ((th4 ^ sw) << 2)) = v;
    }
    __syncthreads();

    // ---- phase B: column gather, scale by x[j], pack bf16, coalesced store ----
    const int c = tid & 15;               // output 16B chunk: j = c*8 .. c*8+7
    float xv[8];
    *(f32x4*)&xv[0] = *(const f32x4*)(xs + c * 8);
    *(f32x4*)&xv[4] = *(const f32x4*)(xs + c * 8 + 4);

    #pragma unroll
    for (int it = 0; it < 4; ++it) {
        int tl = it * 16 + (tid >> 4);    // t_local 0..63
        int ch = tl >> 2, lo = tl & 3;
        unsigned pk4[4];
        #pragma unroll
        for (int p = 0; p < 4; ++p) {
            int j0  = c * 8 + 2 * p;
            int j1  = j0 + 1;
            int sw0 = (j0 ^ (j0 >> 3)) & 15;
            int sw1 = (j1 ^ (j1 >> 3)) & 15;
            float m0 = tile[j0 * 64 + ((ch ^ sw0) << 2) + lo];
            float m1 = tile[j1 * 64 + ((ch ^ sw1) << 2) + lo];
            pk4[p] = pk_bf16(m0 * xv[2 * p], m1 * xv[2 * p + 1]);
        }
        uint4 ov = make_uint4(pk4[0], pk4[1], pk4[2], pk4[3]);
        *(uint4*)(Xm + ((size_t)(half * 64 + tl) * B_TOTAL + b) * NVARS + c * 8) = ov;
    }
}

// ---------------------------------------------------------------------------
// Fused 3-layer per-module MLP, SWAPPED-operand MFMA (A = weights, B = acts):
//   C[row = n, col = b]  ->  each lane holds 4 consecutive n at one b, so the
//   bias+lrelu+bf16 epilogue packs in-lane (cvt_pk + ds_write_b64) and the
//   W2 dot reduces with just 2 shuffles.
// LDS: single 32 KB union buffer (sA [64][128] then sH [64][256]), both with
// 16B-chunk XOR swizzle (chunk ^= row&7) -> all ds_read_b128 at minimum 8-way.
// 33.8 KB total -> 4 blocks/CU.
// MFMA 16x16x32 bf16: A/B lane l -> row (l&15), k=(l>>4)*8+j; C/D col=l&15,
// row=(l>>4)*4+r (m89/m91-verified).
// ---------------------------------------------------------------------------
__global__ __launch_bounds__(256, 4) void k_mlp(
    const unsigned short* __restrict__ Xm,   // [128][4096][128] bf16
    const unsigned short* __restrict__ W0b,  // [128][256][128] bf16
    const float* __restrict__ b0,            // [128][256]
    const unsigned short* __restrict__ W1b,  // [128][256][256] bf16
    const float* __restrict__ b1,            // [128][256]
    const float* __restrict__ W2,            // [128][256]
    const float* __restrict__ b2,            // [128]
    float* __restrict__ hout)                // [4096][128]
{
    const int t     = blockIdx.y;
    const int brow0 = blockIdx.x * 64;
    const int tid   = threadIdx.x;
    const int w     = tid >> 6;
    const int l     = tid & 63;
    const int quad  = l >> 4;
    const int l16   = l & 15;

    __shared__ __align__(16) unsigned short uLds[64 * 256];  // 32 KB union
    __shared__ float hpart[4][64];

    // ---- stage Xm tile -> swizzled sA [64][128] (coalesced reads) ----
    {
        const unsigned short* xsrc = Xm + ((size_t)t * B_TOTAL + brow0) * NVARS;
        #pragma unroll
        for (int it = 0; it < 4; ++it) {
            int slot = it * 256 + tid;
            int bb = slot >> 4;
            int c  = slot & 15;
            uint4 v = *(const uint4*)(xsrc + (size_t)bb * NVARS + c * 8);
            *(uint4*)(uLds + bb * 128 + ((c ^ (bb & 7)) << 3)) = v;
        }
    }
    __syncthreads();

    // ---- layer 0: acc[mt][bt] = W0 . Xm^T  (C rows = n, C cols = b) ----
    f32x4 acc[4][4];
    #pragma unroll
    for (int mt = 0; mt < 4; ++mt)
        #pragma unroll
        for (int bt = 0; bt < 4; ++bt)
            acc[mt][bt] = {0.f, 0.f, 0.f, 0.f};

    const unsigned short* w0p = W0b + ((size_t)t * HID + w * 64 + l16) * NVARS;
    #pragma unroll
    for (int k0 = 0; k0 < NVARS; k0 += 32) {
        const int kc = (k0 >> 3) + quad;          // logical 16B chunk
        bf16x8 bx[4];
        #pragma unroll
        for (int bt = 0; bt < 4; ++bt) {
            int bb = bt * 16 + l16;
            bx[bt] = *(const bf16x8*)(uLds + bb * 128 + ((kc ^ (bb & 7)) << 3));
        }
        #pragma unroll
        for (int mt = 0; mt < 4; ++mt) {
            bf16x8 aw = *(const bf16x8*)(w0p + mt * 16 * NVARS + k0 + quad * 8);
            #pragma unroll
            for (int bt = 0; bt < 4; ++bt)
                acc[mt][bt] = __builtin_amdgcn_mfma_f32_16x16x32_bf16(aw, bx[bt], acc[mt][bt], 0, 0, 0);
        }
    }
    __syncthreads();   // all waves done reading sA -> safe to overwrite as sH

    // ---- epilogue 0: bias + lrelu, packed bf16 pairs -> swizzled sH [64][256]
    #pragma unroll
    for (int mt = 0; mt < 4; ++mt) {
        const int n0 = w * 64 + mt * 16 + quad * 4;          // 4 consecutive n
        f32x4 b0v = *(const f32x4*)(b0 + t * HID + n0);
        const int chunk = n0 >> 3;
        const int h8    = (quad & 1) << 2;                   // ushort offset of 8B half
        #pragma unroll
        for (int bt = 0; bt < 4; ++bt) {
            int bb = bt * 16 + l16;
            float v0 = lrelu(acc[mt][bt][0] + b0v[0]);
            float v1 = lrelu(acc[mt][bt][1] + b0v[1]);
            float v2 = lrelu(acc[mt][bt][2] + b0v[2]);
            float v3 = lrelu(acc[mt][bt][3] + b0v[3]);
            uint2 pv;
            pv.x = pk_bf16(v0, v1);
            pv.y = pk_bf16(v2, v3);
            *(uint2*)(uLds + bb * 256 + ((chunk ^ (bb & 7)) << 3) + h8) = pv;
        }
    }
    __syncthreads();

    // ---- layer 1: acc2[mt][bt] = W1 . H0^T ----
    f32x4 acc2[4][4];
    #pragma unroll
    for (int mt = 0; mt < 4; ++mt)
        #pragma unroll
        for (int bt = 0; bt < 4; ++bt)
            acc2[mt][bt] = {0.f, 0.f, 0.f, 0.f};

    const unsigned short* w1p = W1b + ((size_t)t * HID + w * 64 + l16) * HID;
    #pragma unroll
    for (int k0 = 0; k0 < HID; k0 += 32) {
        const int kc = (k0 >> 3) + quad;
        bf16x8 bh[4];
        #pragma unroll
        for (int bt = 0; bt < 4; ++bt) {
            int bb = bt * 16 + l16;
            bh[bt] = *(const bf16x8*)(uLds + bb * 256 + ((kc ^ (bb & 7)) << 3));
        }
        #pragma unroll
        for (int mt = 0; mt < 4; ++mt) {
            bf16x8 aw = *(const bf16x8*)(w1p + mt * 16 * HID + k0 + quad * 8);
            #pragma unroll
            for (int bt = 0; bt < 4; ++bt)
                acc2[mt][bt] = __builtin_amdgcn_mfma_f32_16x16x32_bf16(aw, bh[bt], acc2[mt][bt], 0, 0, 0);
        }
    }

    // ---- epilogue 1: bias + lrelu, in-lane dot with W2, 2-shuffle reduce ----
    {
        float sacc[4] = {0.f, 0.f, 0.f, 0.f};
        #pragma unroll
        for (int mt = 0; mt < 4; ++mt) {
            const int n0 = w * 64 + mt * 16 + quad * 4;
            f32x4 b1v = *(const f32x4*)(b1 + t * HID + n0);
            f32x4 w2v = *(const f32x4*)(W2 + t * HID + n0);
            #pragma unroll
            for (int bt = 0; bt < 4; ++bt) {
                #pragma unroll
                for (int r = 0; r < 4; ++r) {
                    float v = lrelu(acc2[mt][bt][r] + b1v[r]);
                    sacc[bt] += v * w2v[r];
                }
            }
        }
        #pragma unroll
        for (int bt = 0; bt < 4; ++bt) {
            float s = sacc[bt];
            s += __shfl_xor(s, 16, 64);   // reduce across quads (different n)
            s += __shfl_xor(s, 32, 64);
            if (quad == 0) hpart[w][bt * 16 + l16] = s;
        }
    }
    __syncthreads();

    if (tid < 64) {
        float hv = hpart[0][tid] + hpart[1][tid] + hpart[2][tid] + hpart[3][tid] + b2[t];
        hout[(size_t)(brow0 + tid) * NMOD + t] = hv;
    }
}

// ---------------------------------------------------------------------------
// module2node: out[b][v] = sum_m Wm[v][m] * mask_m2n[b][v][m] * h[b][m] + bm[v]
// 2 threads per v, each streams 64 m's as f32x4 (per-lane sequential lines,
// L1-resident); one LDS partial + pair-sum. No per-v shuffle trees.
// ---------------------------------------------------------------------------
__global__ __launch_bounds__(256) void k_m2n(const float* __restrict__ m2n,
                                             const float* __restrict__ Wm,
                                             const float* __restrict__ bm,
                                             const float* __restrict__ h,
                                             float* __restrict__ out) {
    const int b   = blockIdx.x;
    const int tid = threadIdx.x;
    const int v   = tid >> 1;
    const int hh  = tid & 1;

    __shared__ __align__(16) float hvec[NMOD];
    __shared__ float part[256];

    if (tid < NMOD) hvec[tid] = h[(size_t)b * NMOD + tid];
    __syncthreads();

    const float* mrow = m2n + (size_t)b * (NVARS * NMOD) + v * NMOD + hh * 64;
    const float* wrow = Wm + v * NMOD + hh * 64;

    float s = 0.f;
    #pragma unroll 4
    for (int i = 0; i < 16; ++i) {
        f32x4 mm = *(const f32x4*)(mrow + i * 4);
        f32x4 wm = *(const f32x4*)(wrow + i * 4);
        f32x4 hv = *(const f32x4*)(hvec + hh * 64 + i * 4);   // 2-addr broadcast
        s += wm[0] * mm[0] * hv[0];
        s += wm[1] * mm[1] * hv[1];
        s += wm[2] * mm[2] * hv[2];
        s += wm[3] * mm[3] * hv[3];
    }
    part[tid] = s;
    __syncthreads();

    if (tid < NVARS)
        out[(size_t)b * NVARS + tid] = part[2 * tid] + part[2 * tid + 1] + bm[tid];
}

// ---------------------------------------------------------------------------
extern "C" void kernel_launch(void* const* d_in, const int* in_sizes, int n_in,
                              void* d_out, int out_size, void* d_ws, size_t ws_size,
                              hipStream_t stream) {
    const float* x    = (const float*)d_in[0];
    const float* mn2m = (const float*)d_in[1];
    const float* mm2n = (const float*)d_in[2];
    const float* W0   = (const float*)d_in[3];
    const float* b0   = (const float*)d_in[4];
    const float* W1   = (const float*)d_in[5];
    const float* b1   = (const float*)d_in[6];
    const float* W2   = (const float*)d_in[7];
    const float* b2   = (const float*)d_in[8];
    const float* Wm   = (const float*)d_in[9];
    const float* bm   = (const float*)d_in[10];
    float* out = (float*)d_out;

    // workspace layout (bytes):
    //   Xm  bf16 [128][4096][128]  = 134,217,728
    //   W0b bf16 [128][256][128]   =   8,388,608
    //   W1b bf16 [128][256][256]   =  16,777,216
    //   h   f32  [4096][128]       =   2,097,152     total ~154 MB
    char* ws = (char*)d_ws;
    unsigned short* Xm  = (unsigned short*)(ws);
    unsigned short* W0b = (unsigned short*)(ws + (size_t)134217728);
    unsigned short* W1b = (unsigned short*)(ws + (size_t)142606336);
    float*          hbuf = (float*)(ws + (size_t)159383552);

    k_cvt  <<<4096, 256, 0, stream>>>(W0, (uint2*)W0b, 1048576);
    k_cvt  <<<8192, 256, 0, stream>>>(W1, (uint2*)W1b, 2097152);
    k_maskx<<<dim3(4096, 2), 256, 0, stream>>>(mn2m, x, Xm);
    k_mlp  <<<dim3(64, 128), 256, 0, stream>>>(Xm, W0b, b0, W1b, b1, W2, b2, hbuf);
    k_m2n  <<<4096, 256, 0, stream>>>(mm2n, Wm, bm, hbuf, out);
}

// Round 2
// 812.747 us; speedup vs baseline: 1.1080x; 1.1080x over previous
//
#include <hip/hip_runtime.h>

#define B_TOTAL 4096
#define NVARS   128
#define NMOD    128
#define HID     256

typedef __attribute__((ext_vector_type(8))) __bf16 bf16x8;
typedef __attribute__((ext_vector_type(4))) float  f32x4;

// packed f32->bf16 (RNE), 2 values / instruction
__device__ __forceinline__ unsigned pk_bf16(float lo, float hi) {
    unsigned r;
    asm("v_cvt_pk_bf16_f32 %0, %1, %2" : "=v"(r) : "v"(lo), "v"(hi));
    return r;
}

__device__ __forceinline__ float lrelu(float v) { return v > 0.f ? v : 0.01f * v; }

// ---------------------------------------------------------------------------
// fp32 -> bf16 weight conversion (once per launch; weights then L2/L3-hot)
// ---------------------------------------------------------------------------
__global__ __launch_bounds__(256) void k_cvt(const float* __restrict__ in,
                                             uint2* __restrict__ out, int n4) {
    int i = blockIdx.x * 256 + threadIdx.x;
    if (i < n4) {
        float4 v = ((const float4*)in)[i];
        uint2 o;
        o.x = pk_bf16(v.x, v.y);
        o.y = pk_bf16(v.z, v.w);
        out[i] = o;
    }
}

// ---------------------------------------------------------------------------
// Xm[t][b][j] = bf16( mask_n2m[b][j][t] * x[b][j] )
// grid (b, half): each block transposes a 128j x 64t half-tile via an f32 LDS
// tile [j][t] with 16B-chunk XOR swizzle (conflict-minimal both phases).
// ---------------------------------------------------------------------------
__global__ __launch_bounds__(256) void k_maskx(const float* __restrict__ mask,
                                               const float* __restrict__ x,
                                               unsigned short* __restrict__ Xm) {
    const int b    = blockIdx.x;
    const int half = blockIdx.y;          // t in [half*64, half*64+64)
    const int tid  = threadIdx.x;

    __shared__ __align__(16) float xs[NVARS];
    __shared__ __align__(16) float tile[NVARS * 64];   // [j][t_local], swizzled

    if (tid < NVARS) xs[tid] = x[(size_t)b * NVARS + tid];

    // ---- phase A: mask[b][j][half*64 + ...] -> tile ----
    const float* mrow = mask + (size_t)b * (NVARS * NMOD) + half * 64;
    #pragma unroll
    for (int it = 0; it < 8; ++it) {
        int idx4 = it * 256 + tid;        // 0..2047
        int j    = idx4 >> 4;             // 0..127
        int th4  = idx4 & 15;             // 16B chunk within the 64-float row
        float4 v = *(const float4*)(mrow + (size_t)j * NMOD + th4 * 4);
        int sw = (j ^ (j >> 3)) & 15;
        *(float4*)(tile + j * 64 + ((th4 ^ sw) << 2)) = v;
    }
    __syncthreads();

    // ---- phase B: column gather, scale by x[j], pack bf16, coalesced store ----
    const int c = tid & 15;               // output 16B chunk: j = c*8 .. c*8+7
    float xv[8];
    *(f32x4*)&xv[0] = *(const f32x4*)(xs + c * 8);
    *(f32x4*)&xv[4] = *(const f32x4*)(xs + c * 8 + 4);

    #pragma unroll
    for (int it = 0; it < 4; ++it) {
        int tl = it * 16 + (tid >> 4);    // t_local 0..63
        int ch = tl >> 2, lo = tl & 3;
        unsigned pk4[4];
        #pragma unroll
        for (int p = 0; p < 4; ++p) {
            int j0  = c * 8 + 2 * p;
            int j1  = j0 + 1;
            int sw0 = (j0 ^ (j0 >> 3)) & 15;
            int sw1 = (j1 ^ (j1 >> 3)) & 15;
            float m0 = tile[j0 * 64 + ((ch ^ sw0) << 2) + lo];
            float m1 = tile[j1 * 64 + ((ch ^ sw1) << 2) + lo];
            pk4[p] = pk_bf16(m0 * xv[2 * p], m1 * xv[2 * p + 1]);
        }
        uint4 ov = make_uint4(pk4[0], pk4[1], pk4[2], pk4[3]);
        *(uint4*)(Xm + ((size_t)(half * 64 + tl) * B_TOTAL + b) * NVARS + c * 8) = ov;
    }
}

// ---------------------------------------------------------------------------
// Fused 3-layer per-module MLP, 512 threads = 8 waves, wave tile = 32n x 64b.
// Swapped-operand MFMA (A = weights, B = acts): C[row=n, col=b] -> lane holds
// 4 consecutive n at one b; epilogues are in-lane (cvt_pk pairs, 2-shuffle dot).
// acc = 2x4 fragments = 32 regs -> total pressure ~100 unified, NO SPILL at
// __launch_bounds__(512,2); LDS 34.8 KB -> 4 blocks/CU; occupancy ~20-24 w/CU.
// LDS: 32 KB union (sA [64][128] then sH [64][256]), 16B-chunk XOR swizzle
// (chunk ^= row&7) keeps every ds_read_b128 at the minimal 8-phase.
// MFMA 16x16x32 bf16: A/B lane l -> row (l&15), k=(l>>4)*8+j; C/D col=l&15,
// row=(l>>4)*4+r (m89/m91-verified; identical mapping as passing round-1).
// ---------------------------------------------------------------------------
__global__ __launch_bounds__(512, 2) void k_mlp(
    const unsigned short* __restrict__ Xm,   // [128][4096][128] bf16
    const unsigned short* __restrict__ W0b,  // [128][256][128] bf16
    const float* __restrict__ b0,            // [128][256]
    const unsigned short* __restrict__ W1b,  // [128][256][256] bf16
    const float* __restrict__ b1,            // [128][256]
    const float* __restrict__ W2,            // [128][256]
    const float* __restrict__ b2,            // [128]
    float* __restrict__ hout)                // [4096][128]
{
    const int t     = blockIdx.y;
    const int brow0 = blockIdx.x * 64;
    const int tid   = threadIdx.x;
    const int w     = tid >> 6;              // wave 0..7, owns n in [w*32, w*32+32)
    const int l     = tid & 63;
    const int quad  = l >> 4;
    const int l16   = l & 15;

    __shared__ __align__(16) unsigned short uLds[64 * 256];  // 32 KB union
    __shared__ float hpart[8][64];

    // ---- stage Xm tile -> swizzled sA [64][128] (coalesced reads) ----
    {
        const unsigned short* xsrc = Xm + ((size_t)t * B_TOTAL + brow0) * NVARS;
        #pragma unroll
        for (int it = 0; it < 2; ++it) {
            int slot = it * 512 + tid;
            int bb = slot >> 4;
            int c  = slot & 15;
            uint4 v = *(const uint4*)(xsrc + (size_t)bb * NVARS + c * 8);
            *(uint4*)(uLds + bb * 128 + ((c ^ (bb & 7)) << 3)) = v;
        }
    }
    __syncthreads();

    // ---- layer 0: acc[mt][bt] = W0 . Xm^T  (C rows = n, C cols = b) ----
    f32x4 acc[2][4];
    #pragma unroll
    for (int mt = 0; mt < 2; ++mt)
        #pragma unroll
        for (int bt = 0; bt < 4; ++bt)
            acc[mt][bt] = {0.f, 0.f, 0.f, 0.f};

    const unsigned short* w0p = W0b + ((size_t)t * HID + w * 32 + l16) * NVARS;
    #pragma unroll
    for (int k0 = 0; k0 < NVARS; k0 += 32) {
        const int kc = (k0 >> 3) + quad;          // logical 16B chunk
        bf16x8 bx[4];
        #pragma unroll
        for (int bt = 0; bt < 4; ++bt) {
            int bb = bt * 16 + l16;
            bx[bt] = *(const bf16x8*)(uLds + bb * 128 + ((kc ^ (bb & 7)) << 3));
        }
        #pragma unroll
        for (int mt = 0; mt < 2; ++mt) {
            bf16x8 aw = *(const bf16x8*)(w0p + mt * 16 * NVARS + k0 + quad * 8);
            #pragma unroll
            for (int bt = 0; bt < 4; ++bt)
                acc[mt][bt] = __builtin_amdgcn_mfma_f32_16x16x32_bf16(aw, bx[bt], acc[mt][bt], 0, 0, 0);
        }
    }
    __syncthreads();   // all waves done reading sA -> safe to overwrite as sH

    // ---- epilogue 0: bias + lrelu, packed bf16 pairs -> swizzled sH [64][256]
    #pragma unroll
    for (int mt = 0; mt < 2; ++mt) {
        const int n0 = w * 32 + mt * 16 + quad * 4;          // 4 consecutive n
        f32x4 b0v = *(const f32x4*)(b0 + t * HID + n0);
        const int chunk = n0 >> 3;
        const int h8    = (quad & 1) << 2;                   // ushort offset of 8B half
        #pragma unroll
        for (int bt = 0; bt < 4; ++bt) {
            int bb = bt * 16 + l16;
            float v0 = lrelu(acc[mt][bt][0] + b0v[0]);
            float v1 = lrelu(acc[mt][bt][1] + b0v[1]);
            float v2 = lrelu(acc[mt][bt][2] + b0v[2]);
            float v3 = lrelu(acc[mt][bt][3] + b0v[3]);
            uint2 pv;
            pv.x = pk_bf16(v0, v1);
            pv.y = pk_bf16(v2, v3);
            *(uint2*)(uLds + bb * 256 + ((chunk ^ (bb & 7)) << 3) + h8) = pv;
        }
    }
    __syncthreads();

    // ---- layer 1: acc2[mt][bt] = W1 . H0^T ----
    f32x4 acc2[2][4];
    #pragma unroll
    for (int mt = 0; mt < 2; ++mt)
        #pragma unroll
        for (int bt = 0; bt < 4; ++bt)
            acc2[mt][bt] = {0.f, 0.f, 0.f, 0.f};

    const unsigned short* w1p = W1b + ((size_t)t * HID + w * 32 + l16) * HID;
    #pragma unroll
    for (int k0 = 0; k0 < HID; k0 += 32) {
        const int kc = (k0 >> 3) + quad;
        bf16x8 bh[4];
        #pragma unroll
        for (int bt = 0; bt < 4; ++bt) {
            int bb = bt * 16 + l16;
            bh[bt] = *(const bf16x8*)(uLds + bb * 256 + ((kc ^ (bb & 7)) << 3));
        }
        #pragma unroll
        for (int mt = 0; mt < 2; ++mt) {
            bf16x8 aw = *(const bf16x8*)(w1p + mt * 16 * HID + k0 + quad * 8);
            #pragma unroll
            for (int bt = 0; bt < 4; ++bt)
                acc2[mt][bt] = __builtin_amdgcn_mfma_f32_16x16x32_bf16(aw, bh[bt], acc2[mt][bt], 0, 0, 0);
        }
    }

    // ---- epilogue 1: bias + lrelu, in-lane dot with W2, 2-shuffle reduce ----
    {
        float sacc[4] = {0.f, 0.f, 0.f, 0.f};
        #pragma unroll
        for (int mt = 0; mt < 2; ++mt) {
            const int n0 = w * 32 + mt * 16 + quad * 4;
            f32x4 b1v = *(const f32x4*)(b1 + t * HID + n0);
            f32x4 w2v = *(const f32x4*)(W2 + t * HID + n0);
            #pragma unroll
            for (int bt = 0; bt < 4; ++bt) {
                #pragma unroll
                for (int r = 0; r < 4; ++r) {
                    float v = lrelu(acc2[mt][bt][r] + b1v[r]);
                    sacc[bt] += v * w2v[r];
                }
            }
        }
        #pragma unroll
        for (int bt = 0; bt < 4; ++bt) {
            float s = sacc[bt];
            s += __shfl_xor(s, 16, 64);   // reduce across quads (different n)
            s += __shfl_xor(s, 32, 64);
            if (quad == 0) hpart[w][bt * 16 + l16] = s;
        }
    }
    __syncthreads();

    if (tid < 64) {
        float hv = hpart[0][tid] + hpart[1][tid] + hpart[2][tid] + hpart[3][tid]
                 + hpart[4][tid] + hpart[5][tid] + hpart[6][tid] + hpart[7][tid] + b2[t];
        hout[(size_t)(brow0 + tid) * NMOD + t] = hv;
    }
}

// ---------------------------------------------------------------------------
// module2node: out[b][v] = sum_m Wm[v][m] * mask_m2n[b][v][m] * h[b][m] + bm[v]
// 16 lanes per v (each lane owns m = m16*8..m16*8+7): mask/Wm reads fully
// coalesced (512 B contiguous per 16-lane group), h slice register-resident
// (m16 loop-invariant), 4-level shuffle per v -> 32 shuffles/thread total.
// ---------------------------------------------------------------------------
__global__ __launch_bounds__(256) void k_m2n(const float* __restrict__ m2n,
                                             const float* __restrict__ Wm,
                                             const float* __restrict__ bm,
                                             const float* __restrict__ h,
                                             float* __restrict__ out) {
    const int b    = blockIdx.x;
    const int tid  = threadIdx.x;
    const int w    = tid >> 6;
    const int l    = tid & 63;
    const int vsub = l >> 4;       // 4 v's in flight per wave
    const int m16  = l & 15;       // lane's m-chunk

    __shared__ __align__(16) float hvec[NMOD];
    __shared__ float outv[NVARS];

    if (tid < NMOD) hvec[tid] = h[(size_t)b * NMOD + tid];
    __syncthreads();

    f32x4 h0 = *(const f32x4*)(hvec + m16 * 8);
    f32x4 h1 = *(const f32x4*)(hvec + m16 * 8 + 4);

    const float* mbase = m2n + (size_t)b * (NVARS * NMOD);

    #pragma unroll
    for (int it = 0; it < 8; ++it) {
        int v = w * 32 + it * 4 + vsub;
        const float* mr = mbase + v * NMOD + m16 * 8;
        const float* wr = Wm + v * NMOD + m16 * 8;
        f32x4 m0 = *(const f32x4*)(mr);
        f32x4 m1 = *(const f32x4*)(mr + 4);
        f32x4 w0 = *(const f32x4*)(wr);
        f32x4 w1 = *(const f32x4*)(wr + 4);
        float s = w0[0] * m0[0] * h0[0] + w0[1] * m0[1] * h0[1]
                + w0[2] * m0[2] * h0[2] + w0[3] * m0[3] * h0[3]
                + w1[0] * m1[0] * h1[0] + w1[1] * m1[1] * h1[1]
                + w1[2] * m1[2] * h1[2] + w1[3] * m1[3] * h1[3];
        s += __shfl_xor(s, 1, 64);
        s += __shfl_xor(s, 2, 64);
        s += __shfl_xor(s, 4, 64);
        s += __shfl_xor(s, 8, 64);
        if (m16 == 0) outv[v] = s;
    }
    __syncthreads();

    if (tid < NVARS) out[(size_t)b * NVARS + tid] = outv[tid] + bm[tid];
}

// ---------------------------------------------------------------------------
extern "C" void kernel_launch(void* const* d_in, const int* in_sizes, int n_in,
                              void* d_out, int out_size, void* d_ws, size_t ws_size,
                              hipStream_t stream) {
    const float* x    = (const float*)d_in[0];
    const float* mn2m = (const float*)d_in[1];
    const float* mm2n = (const float*)d_in[2];
    const float* W0   = (const float*)d_in[3];
    const float* b0   = (const float*)d_in[4];
    const float* W1   = (const float*)d_in[5];
    const float* b1   = (const float*)d_in[6];
    const float* W2   = (const float*)d_in[7];
    const float* b2   = (const float*)d_in[8];
    const float* Wm   = (const float*)d_in[9];
    const float* bm   = (const float*)d_in[10];
    float* out = (float*)d_out;

    // workspace layout (bytes):
    //   Xm  bf16 [128][4096][128]  = 134,217,728
    //   W0b bf16 [128][256][128]   =   8,388,608
    //   W1b bf16 [128][256][256]   =  16,777,216
    //   h   f32  [4096][128]       =   2,097,152     total ~154 MB
    char* ws = (char*)d_ws;
    unsigned short* Xm  = (unsigned short*)(ws);
    unsigned short* W0b = (unsigned short*)(ws + (size_t)134217728);
    unsigned short* W1b = (unsigned short*)(ws + (size_t)142606336);
    float*          hbuf = (float*)(ws + (size_t)159383552);

    k_cvt  <<<4096, 256, 0, stream>>>(W0, (uint2*)W0b, 1048576);
    k_cvt  <<<8192, 256, 0, stream>>>(W1, (uint2*)W1b, 2097152);
    k_maskx<<<dim3(4096, 2), 256, 0, stream>>>(mn2m, x, Xm);
    k_mlp  <<<dim3(64, 128), 512, 0, stream>>>(Xm, W0b, b0, W1b, b1, W2, b2, hbuf);
    k_m2n  <<<4096, 256, 0, stream>>>(mm2n, Wm, bm, hbuf, out);
}

// Round 3
// 779.771 us; speedup vs baseline: 1.1548x; 1.0423x over previous
//
#include <hip/hip_runtime.h>

#define B_TOTAL 4096
#define NVARS   128
#define NMOD    128
#define HID     256

typedef __attribute__((ext_vector_type(8))) __bf16 bf16x8;
typedef __attribute__((ext_vector_type(4))) float  f32x4;

// packed f32->bf16 (RNE), 2 values / instruction
__device__ __forceinline__ unsigned pk_bf16(float lo, float hi) {
    unsigned r;
    asm("v_cvt_pk_bf16_f32 %0, %1, %2" : "=v"(r) : "v"(lo), "v"(hi));
    return r;
}

__device__ __forceinline__ float lrelu(float v) { return v > 0.f ? v : 0.01f * v; }

// ---------------------------------------------------------------------------
// fp32 -> bf16 conversion for W0 and W1 in one launch
// ---------------------------------------------------------------------------
__global__ __launch_bounds__(256) void k_cvt2(const float* __restrict__ a,
                                              uint2* __restrict__ oa, int na4,
                                              const float* __restrict__ b,
                                              uint2* __restrict__ ob, int nb4) {
    int i = blockIdx.x * 256 + threadIdx.x;
    const float* src; uint2* dst; int idx;
    if (i < na4) { src = a; dst = oa; idx = i; }
    else {
        idx = i - na4;
        if (idx >= nb4) return;
        src = b; dst = ob;
    }
    float4 v = ((const float4*)src)[idx];
    uint2 o;
    o.x = pk_bf16(v.x, v.y);
    o.y = pk_bf16(v.z, v.w);
    dst[idx] = o;
}

// ---------------------------------------------------------------------------
// Xm[t][b][j] = bf16( mask_n2m[b][j][t] * x[b][j] )
// grid (b, half): each block transposes a 128j x 64t half-tile via an f32 LDS
// tile [j][t] with 16B-chunk XOR swizzle (conflict-minimal both phases).
// ---------------------------------------------------------------------------
__global__ __launch_bounds__(256) void k_maskx(const float* __restrict__ mask,
                                               const float* __restrict__ x,
                                               unsigned short* __restrict__ Xm) {
    const int b    = blockIdx.x;
    const int half = blockIdx.y;          // t in [half*64, half*64+64)
    const int tid  = threadIdx.x;

    __shared__ __align__(16) float xs[NVARS];
    __shared__ __align__(16) float tile[NVARS * 64];   // [j][t_local], swizzled

    if (tid < NVARS) xs[tid] = x[(size_t)b * NVARS + tid];

    // ---- phase A: mask[b][j][half*64 + ...] -> tile ----
    const float* mrow = mask + (size_t)b * (NVARS * NMOD) + half * 64;
    #pragma unroll
    for (int it = 0; it < 8; ++it) {
        int idx4 = it * 256 + tid;        // 0..2047
        int j    = idx4 >> 4;             // 0..127
        int th4  = idx4 & 15;             // 16B chunk within the 64-float row
        float4 v = *(const float4*)(mrow + (size_t)j * NMOD + th4 * 4);
        int sw = (j ^ (j >> 3)) & 15;
        *(float4*)(tile + j * 64 + ((th4 ^ sw) << 2)) = v;
    }
    __syncthreads();

    // ---- phase B: column gather, scale by x[j], pack bf16, coalesced store ----
    const int c = tid & 15;               // output 16B chunk: j = c*8 .. c*8+7
    float xv[8];
    *(f32x4*)&xv[0] = *(const f32x4*)(xs + c * 8);
    *(f32x4*)&xv[4] = *(const f32x4*)(xs + c * 8 + 4);

    #pragma unroll
    for (int it = 0; it < 4; ++it) {
        int tl = it * 16 + (tid >> 4);    // t_local 0..63
        int ch = tl >> 2, lo = tl & 3;
        unsigned pk4[4];
        #pragma unroll
        for (int p = 0; p < 4; ++p) {
            int j0  = c * 8 + 2 * p;
            int j1  = j0 + 1;
            int sw0 = (j0 ^ (j0 >> 3)) & 15;
            int sw1 = (j1 ^ (j1 >> 3)) & 15;
            float m0 = tile[j0 * 64 + ((ch ^ sw0) << 2) + lo];
            float m1 = tile[j1 * 64 + ((ch ^ sw1) << 2) + lo];
            pk4[p] = pk_bf16(m0 * xv[2 * p], m1 * xv[2 * p + 1]);
        }
        uint4 ov = make_uint4(pk4[0], pk4[1], pk4[2], pk4[3]);
        *(uint4*)(Xm + ((size_t)(half * 64 + tl) * B_TOTAL + b) * NVARS + c * 8) = ov;
    }
}

// ---------------------------------------------------------------------------
// Fused 3-layer per-module MLP, 512 threads = 8 waves, wave tile = 32n x 64b.
// Swapped-operand MFMA (A = weights, B = acts): C[row=n, col=b].
//
// KEY CHANGE (round 3): t-major XCD swizzle. Dispatch-linear id round-robins
// over 8 XCDs; we assign each XCD 16 fixed modules (t = xcd + 8*k). Per-XCD
// weight working set = 16 x 192 KB = 3 MB < 4 MB L2 -> the 1.57 GB aggregate
// weight re-read stream is served by the local L2 (~200cy, 34.5 TB/s agg)
// instead of L3 (~600cy) which was the round-0/2 limiter (MfmaUtil pinned
// at 17.5%, HBM 8.7%, time invariant across structures).
//
// Also: sA/sH un-unioned (16+32 KB separate) -> post-layer-0 barrier removed
// (3 barriers/block instead of 4). 50 KB LDS -> 3 blocks/CU, same as the
// register-bound limit (76 unified regs -> 3 blocks), so no occupancy loss.
//
// MFMA 16x16x32 bf16: A/B lane l -> row (l&15), k=(l>>4)*8+j; C/D col=l&15,
// row=(l>>4)*4+r (m89/m91-verified; identical mapping as passing rounds).
// ---------------------------------------------------------------------------
__global__ __launch_bounds__(512, 2) void k_mlp(
    const unsigned short* __restrict__ Xm,   // [128][4096][128] bf16
    const unsigned short* __restrict__ W0b,  // [128][256][128] bf16
    const float* __restrict__ b0,            // [128][256]
    const unsigned short* __restrict__ W1b,  // [128][256][256] bf16
    const float* __restrict__ b1,            // [128][256]
    const float* __restrict__ W2,            // [128][256]
    const float* __restrict__ b2,            // [128]
    float* __restrict__ hout)                // [4096][128]
{
    // ---- t-major XCD swizzle (bijective on 8192 blocks) ----
    const unsigned lid  = blockIdx.x + blockIdx.y * 64u;   // dispatch-linear
    const unsigned xcd  = lid & 7u;                        // round-robin XCD
    const unsigned slot = lid >> 3;                        // per-XCD sequence
    const int t     = (int)(xcd + 8u * (slot & 15u));      // 16 modules per XCD
    const int brow0 = (int)(slot >> 4) * 64;               // 64 b-tiles per t

    const int tid   = threadIdx.x;
    const int w     = tid >> 6;              // wave 0..7, owns n in [w*32, w*32+32)
    const int l     = tid & 63;
    const int quad  = l >> 4;
    const int l16   = l & 15;

    __shared__ __align__(16) unsigned short sA[64 * 128];  // 16 KB Xm tile
    __shared__ __align__(16) unsigned short sH[64 * 256];  // 32 KB H0 tile
    __shared__ float hpart[8][64];

    // ---- stage Xm tile -> swizzled sA [64][128] (coalesced reads) ----
    {
        const unsigned short* xsrc = Xm + ((size_t)t * B_TOTAL + brow0) * NVARS;
        #pragma unroll
        for (int it = 0; it < 2; ++it) {
            int slot2 = it * 512 + tid;
            int bb = slot2 >> 4;
            int c  = slot2 & 15;
            uint4 v = *(const uint4*)(xsrc + (size_t)bb * NVARS + c * 8);
            *(uint4*)(sA + bb * 128 + ((c ^ (bb & 7)) << 3)) = v;
        }
    }
    __syncthreads();

    // ---- layer 0: acc[mt][bt] = W0 . Xm^T  (C rows = n, C cols = b) ----
    f32x4 acc[2][4];
    #pragma unroll
    for (int mt = 0; mt < 2; ++mt)
        #pragma unroll
        for (int bt = 0; bt < 4; ++bt)
            acc[mt][bt] = {0.f, 0.f, 0.f, 0.f};

    const unsigned short* w0p = W0b + ((size_t)t * HID + w * 32 + l16) * NVARS;
    #pragma unroll
    for (int k0 = 0; k0 < NVARS; k0 += 32) {
        const int kc = (k0 >> 3) + quad;          // logical 16B chunk
        bf16x8 bx[4];
        #pragma unroll
        for (int bt = 0; bt < 4; ++bt) {
            int bb = bt * 16 + l16;
            bx[bt] = *(const bf16x8*)(sA + bb * 128 + ((kc ^ (bb & 7)) << 3));
        }
        #pragma unroll
        for (int mt = 0; mt < 2; ++mt) {
            bf16x8 aw = *(const bf16x8*)(w0p + mt * 16 * NVARS + k0 + quad * 8);
            #pragma unroll
            for (int bt = 0; bt < 4; ++bt)
                acc[mt][bt] = __builtin_amdgcn_mfma_f32_16x16x32_bf16(aw, bx[bt], acc[mt][bt], 0, 0, 0);
        }
    }
    // NOTE: no barrier here — epilogue 0 writes sH, a different buffer than sA.

    // ---- epilogue 0: bias + lrelu, packed bf16 pairs -> swizzled sH [64][256]
    #pragma unroll
    for (int mt = 0; mt < 2; ++mt) {
        const int n0 = w * 32 + mt * 16 + quad * 4;          // 4 consecutive n
        f32x4 b0v = *(const f32x4*)(b0 + t * HID + n0);
        const int chunk = n0 >> 3;
        const int h8    = (quad & 1) << 2;                   // ushort offset of 8B half
        #pragma unroll
        for (int bt = 0; bt < 4; ++bt) {
            int bb = bt * 16 + l16;
            float v0 = lrelu(acc[mt][bt][0] + b0v[0]);
            float v1 = lrelu(acc[mt][bt][1] + b0v[1]);
            float v2 = lrelu(acc[mt][bt][2] + b0v[2]);
            float v3 = lrelu(acc[mt][bt][3] + b0v[3]);
            uint2 pv;
            pv.x = pk_bf16(v0, v1);
            pv.y = pk_bf16(v2, v3);
            *(uint2*)(sH + bb * 256 + ((chunk ^ (bb & 7)) << 3) + h8) = pv;
        }
    }
    __syncthreads();

    // ---- layer 1: acc2[mt][bt] = W1 . H0^T ----
    f32x4 acc2[2][4];
    #pragma unroll
    for (int mt = 0; mt < 2; ++mt)
        #pragma unroll
        for (int bt = 0; bt < 4; ++bt)
            acc2[mt][bt] = {0.f, 0.f, 0.f, 0.f};

    const unsigned short* w1p = W1b + ((size_t)t * HID + w * 32 + l16) * HID;
    #pragma unroll
    for (int k0 = 0; k0 < HID; k0 += 32) {
        const int kc = (k0 >> 3) + quad;
        bf16x8 bh[4];
        #pragma unroll
        for (int bt = 0; bt < 4; ++bt) {
            int bb = bt * 16 + l16;
            bh[bt] = *(const bf16x8*)(sH + bb * 256 + ((kc ^ (bb & 7)) << 3));
        }
        #pragma unroll
        for (int mt = 0; mt < 2; ++mt) {
            bf16x8 aw = *(const bf16x8*)(w1p + mt * 16 * HID + k0 + quad * 8);
            #pragma unroll
            for (int bt = 0; bt < 4; ++bt)
                acc2[mt][bt] = __builtin_amdgcn_mfma_f32_16x16x32_bf16(aw, bh[bt], acc2[mt][bt], 0, 0, 0);
        }
    }

    // ---- epilogue 1: bias + lrelu, in-lane dot with W2, 2-shuffle reduce ----
    {
        float sacc[4] = {0.f, 0.f, 0.f, 0.f};
        #pragma unroll
        for (int mt = 0; mt < 2; ++mt) {
            const int n0 = w * 32 + mt * 16 + quad * 4;
            f32x4 b1v = *(const f32x4*)(b1 + t * HID + n0);
            f32x4 w2v = *(const f32x4*)(W2 + t * HID + n0);
            #pragma unroll
            for (int bt = 0; bt < 4; ++bt) {
                #pragma unroll
                for (int r = 0; r < 4; ++r) {
                    float v = lrelu(acc2[mt][bt][r] + b1v[r]);
                    sacc[bt] += v * w2v[r];
                }
            }
        }
        #pragma unroll
        for (int bt = 0; bt < 4; ++bt) {
            float s = sacc[bt];
            s += __shfl_xor(s, 16, 64);   // reduce across quads (different n)
            s += __shfl_xor(s, 32, 64);
            if (quad == 0) hpart[w][bt * 16 + l16] = s;
        }
    }
    __syncthreads();

    if (tid < 64) {
        float hv = hpart[0][tid] + hpart[1][tid] + hpart[2][tid] + hpart[3][tid]
                 + hpart[4][tid] + hpart[5][tid] + hpart[6][tid] + hpart[7][tid] + b2[t];
        hout[(size_t)(brow0 + tid) * NMOD + t] = hv;
    }
}

// ---------------------------------------------------------------------------
// module2node: out[b][v] = sum_m Wm[v][m] * mask_m2n[b][v][m] * h[b][m] + bm[v]
// 16 lanes per v (each lane owns m = m16*8..m16*8+7): mask/Wm reads fully
// coalesced (512 B contiguous per 16-lane group), h slice register-resident
// (m16 loop-invariant), 4-level shuffle per v -> 32 shuffles/thread total.
// ---------------------------------------------------------------------------
__global__ __launch_bounds__(256) void k_m2n(const float* __restrict__ m2n,
                                             const float* __restrict__ Wm,
                                             const float* __restrict__ bm,
                                             const float* __restrict__ h,
                                             float* __restrict__ out) {
    const int b    = blockIdx.x;
    const int tid  = threadIdx.x;
    const int w    = tid >> 6;
    const int l    = tid & 63;
    const int vsub = l >> 4;       // 4 v's in flight per wave
    const int m16  = l & 15;       // lane's m-chunk

    __shared__ __align__(16) float hvec[NMOD];
    __shared__ float outv[NVARS];

    if (tid < NMOD) hvec[tid] = h[(size_t)b * NMOD + tid];
    __syncthreads();

    f32x4 h0 = *(const f32x4*)(hvec + m16 * 8);
    f32x4 h1 = *(const f32x4*)(hvec + m16 * 8 + 4);

    const float* mbase = m2n + (size_t)b * (NVARS * NMOD);

    #pragma unroll
    for (int it = 0; it < 8; ++it) {
        int v = w * 32 + it * 4 + vsub;
        const float* mr = mbase + v * NMOD + m16 * 8;
        const float* wr = Wm + v * NMOD + m16 * 8;
        f32x4 m0 = *(const f32x4*)(mr);
        f32x4 m1 = *(const f32x4*)(mr + 4);
        f32x4 w0 = *(const f32x4*)(wr);
        f32x4 w1 = *(const f32x4*)(wr + 4);
        float s = w0[0] * m0[0] * h0[0] + w0[1] * m0[1] * h0[1]
                + w0[2] * m0[2] * h0[2] + w0[3] * m0[3] * h0[3]
                + w1[0] * m1[0] * h1[0] + w1[1] * m1[1] * h1[1]
                + w1[2] * m1[2] * h1[2] + w1[3] * m1[3] * h1[3];
        s += __shfl_xor(s, 1, 64);
        s += __shfl_xor(s, 2, 64);
        s += __shfl_xor(s, 4, 64);
        s += __shfl_xor(s, 8, 64);
        if (m16 == 0) outv[v] = s;
    }
    __syncthreads();

    if (tid < NVARS) out[(size_t)b * NVARS + tid] = outv[tid] + bm[tid];
}

// ---------------------------------------------------------------------------
extern "C" void kernel_launch(void* const* d_in, const int* in_sizes, int n_in,
                              void* d_out, int out_size, void* d_ws, size_t ws_size,
                              hipStream_t stream) {
    const float* x    = (const float*)d_in[0];
    const float* mn2m = (const float*)d_in[1];
    const float* mm2n = (const float*)d_in[2];
    const float* W0   = (const float*)d_in[3];
    const float* b0   = (const float*)d_in[4];
    const float* W1   = (const float*)d_in[5];
    const float* b1   = (const float*)d_in[6];
    const float* W2   = (const float*)d_in[7];
    const float* b2   = (const float*)d_in[8];
    const float* Wm   = (const float*)d_in[9];
    const float* bm   = (const float*)d_in[10];
    float* out = (float*)d_out;

    // workspace layout (bytes):
    //   Xm  bf16 [128][4096][128]  = 134,217,728
    //   W0b bf16 [128][256][128]   =   8,388,608
    //   W1b bf16 [128][256][256]   =  16,777,216
    //   h   f32  [4096][128]       =   2,097,152     total ~154 MB
    char* ws = (char*)d_ws;
    unsigned short* Xm  = (unsigned short*)(ws);
    unsigned short* W0b = (unsigned short*)(ws + (size_t)134217728);
    unsigned short* W1b = (unsigned short*)(ws + (size_t)142606336);
    float*          hbuf = (float*)(ws + (size_t)159383552);

    k_cvt2 <<<12288, 256, 0, stream>>>(W0, (uint2*)W0b, 1048576,
                                       W1, (uint2*)W1b, 2097152);
    k_maskx<<<dim3(4096, 2), 256, 0, stream>>>(mn2m, x, Xm);
    k_mlp  <<<dim3(64, 128), 512, 0, stream>>>(Xm, W0b, b0, W1b, b1, W2, b2, hbuf);
    k_m2n  <<<4096, 256, 0, stream>>>(mm2n, Wm, bm, hbuf, out);
}